// Round 1
// baseline (376.196 us; speedup 1.0000x reference)
//
#include <hip/hip_runtime.h>

typedef __attribute__((ext_vector_type(8))) short bhalf8;
typedef __attribute__((ext_vector_type(4))) float floatx4;

#define ALPHA_LR 0.2f

__device__ __forceinline__ unsigned short f2bf(float f) {
  union { float f; unsigned int u; } v; v.f = f;
  unsigned int r = v.u + 0x7fffu + ((v.u >> 16) & 1u);
  return (unsigned short)(r >> 16);
}

// ---------------------------------------------------------------------------
// K1: Wh = h @ W  (fp32), writes Wh fp32 [B*N][256] and WhPack bf16 tiled
//     WhPack layout: [B][jt=64][f=256][j'=32]  (j = jt*32 + j')
// grid 256 blocks x 256 threads; block = 64 rows x 256 cols
// ---------------------------------------------------------------------------
__global__ __launch_bounds__(256) void k1_gemm(const float* __restrict__ h,
                                               const float* __restrict__ W,
                                               float* __restrict__ Wh,
                                               unsigned short* __restrict__ WhPack) {
  __shared__ float hs[64][256];  // 64 KB
  const int t = threadIdx.x;
  const long r0 = (long)blockIdx.x * 64;

  // stage h tile (coalesced float4)
  const float4* hg = (const float4*)(h + r0 * 256);
  float4* hsv = (float4*)hs;
#pragma unroll
  for (int rep = 0; rep < 16; rep++) hsv[rep * 256 + t] = hg[rep * 256 + t];
  __syncthreads();

  float acc[64];
#pragma unroll
  for (int i = 0; i < 64; i++) acc[i] = 0.f;

  for (int k = 0; k < 256; k += 4) {
    float w0 = W[(k + 0) * 256 + t];
    float w1 = W[(k + 1) * 256 + t];
    float w2 = W[(k + 2) * 256 + t];
    float w3 = W[(k + 3) * 256 + t];
#pragma unroll
    for (int i = 0; i < 64; i++) {
      float4 hv = *(const float4*)&hs[i][k];  // broadcast LDS read
      acc[i] = fmaf(hv.x, w0, fmaf(hv.y, w1, fmaf(hv.z, w2, fmaf(hv.w, w3, acc[i]))));
    }
  }

  // fp32 Wh (coalesced per row)
#pragma unroll
  for (int i = 0; i < 64; i++) Wh[(r0 + i) * 256 + t] = acc[i];

  // bf16 packed, transposed-tiled: thread t owns column f=t for 64 rows
  const int b = (int)(r0 >> 11), n0 = (int)(r0 & 2047);
  const int jt0 = n0 >> 5;
#pragma unroll
  for (int half = 0; half < 2; half++) {
    unsigned short buf[32];
#pragma unroll
    for (int q = 0; q < 32; q++) buf[q] = f2bf(acc[half * 32 + q]);
    unsigned short* dst = WhPack + ((long)((b * 64 + jt0 + half) * 256 + t)) * 32;
    int4* d4 = (int4*)dst;
    const int4* s4 = (const int4*)buf;
    d4[0] = s4[0]; d4[1] = s4[1]; d4[2] = s4[2]; d4[3] = s4[3];
  }
}

// ---------------------------------------------------------------------------
// K1b: s1[r] = Wh[r,:] . a1 ; s2[r] = Wh[r,:] . a2   (one wave per row)
// ---------------------------------------------------------------------------
__global__ __launch_bounds__(256) void k1b_s(const float* __restrict__ Wh,
                                             const float* __restrict__ a,
                                             float* __restrict__ s1,
                                             float* __restrict__ s2) {
  const int t = threadIdx.x;
  const int lane = t & 63;
  const long r = (long)blockIdx.x * 4 + (t >> 6);
  const float4* row = (const float4*)(Wh + r * 256);
  const float4* a1 = (const float4*)a;
  const float4* a2 = (const float4*)(a + 256);
  float4 wv = row[lane], v1 = a1[lane], v2 = a2[lane];
  float p1 = wv.x * v1.x + wv.y * v1.y + wv.z * v1.z + wv.w * v1.w;
  float p2 = wv.x * v2.x + wv.y * v2.y + wv.z * v2.z + wv.w * v2.w;
  for (int o = 32; o; o >>= 1) { p1 += __shfl_xor(p1, o); p2 += __shfl_xor(p2, o); }
  if (lane == 0) { s1[r] = p1; s2[r] = p2; }
}

// ---------------------------------------------------------------------------
// K2: per row r=(b,i): M = leaky(s1 + max_{adj} s2) (leaky monotonic),
//     linv = 1/sum(exp(leaky(s1+s2_j)-M)), and pack adj row into 64 u32 words.
// grid 16384 blocks x 256 threads (thread t owns j = 8t..8t+7)
// ---------------------------------------------------------------------------
__global__ __launch_bounds__(256) void k2_stats(const int* __restrict__ adj,
                                                const float* __restrict__ s1,
                                                const float* __restrict__ s2,
                                                float* __restrict__ Mv,
                                                float* __restrict__ linv,
                                                unsigned int* __restrict__ packed) {
  const int t = threadIdx.x;
  const long r = blockIdx.x;
  const int b = (int)(r >> 11);
  __shared__ float red[4];
  __shared__ int redi[4];
  __shared__ unsigned char bytes[256];

  const int4* arow = (const int4*)(adj + r * 2048);
  int4 a0 = arow[t * 2], a1 = arow[t * 2 + 1];
  unsigned int m8 = (unsigned)(a0.x > 0) | ((unsigned)(a0.y > 0) << 1) |
                    ((unsigned)(a0.z > 0) << 2) | ((unsigned)(a0.w > 0) << 3) |
                    ((unsigned)(a1.x > 0) << 4) | ((unsigned)(a1.y > 0) << 5) |
                    ((unsigned)(a1.z > 0) << 6) | ((unsigned)(a1.w > 0) << 7);

  int cnt = __popc(m8);
  for (int o = 32; o; o >>= 1) cnt += __shfl_xor(cnt, o);
  if ((t & 63) == 0) redi[t >> 6] = cnt;
  __syncthreads();
  int total = redi[0] + redi[1] + redi[2] + redi[3];
  if (total == 0) m8 = 0xFFu;  // degenerate row: avoid 0/0 (prob ~0)

  const float4* s2p = (const float4*)(s2 + (long)b * 2048);
  float4 v0 = s2p[t * 2], v1 = s2p[t * 2 + 1];
  float sv[8] = {v0.x, v0.y, v0.z, v0.w, v1.x, v1.y, v1.z, v1.w};

  float mx = -INFINITY;
#pragma unroll
  for (int q = 0; q < 8; q++)
    if ((m8 >> q) & 1) mx = fmaxf(mx, sv[q]);
  for (int o = 32; o; o >>= 1) mx = fmaxf(mx, __shfl_xor(mx, o));
  if ((t & 63) == 0) red[t >> 6] = mx;
  __syncthreads();
  mx = fmaxf(fmaxf(red[0], red[1]), fmaxf(red[2], red[3]));

  const float s1i = s1[r];
  const float xm = s1i + mx;
  const float M = xm > 0.f ? xm : ALPHA_LR * xm;

  float lsum = 0.f;
#pragma unroll
  for (int q = 0; q < 8; q++) {
    if ((m8 >> q) & 1) {
      float x = s1i + sv[q];
      float le = x > 0.f ? x : ALPHA_LR * x;
      lsum += __expf(le - M);
    }
  }
  for (int o = 32; o; o >>= 1) lsum += __shfl_xor(lsum, o);
  __syncthreads();  // protect red[] reuse
  if ((t & 63) == 0) red[t >> 6] = lsum;
  __syncthreads();
  lsum = red[0] + red[1] + red[2] + red[3];

  if (t == 0) { Mv[r] = M; linv[r] = 1.f / lsum; }

  bytes[t] = (unsigned char)m8;
  __syncthreads();
  if (t < 64) {
    unsigned int w = (unsigned)bytes[t * 4] | ((unsigned)bytes[t * 4 + 1] << 8) |
                     ((unsigned)bytes[t * 4 + 2] << 16) | ((unsigned)bytes[t * 4 + 3] << 24);
    packed[r * 64 + t] = w;
  }
}

// ---------------------------------------------------------------------------
// K3: out = elu( (P @ Wh) * linv ), P computed on the fly from packed bits.
// grid (32, 8) x 512 threads. Block: 64 rows x 256 f. 8 waves, wave tile 32x64.
// MFMA 16x16x32 bf16: A = P (M=i, K=j), B = WhT (K=j, N=f).
// ---------------------------------------------------------------------------
__global__ __launch_bounds__(512) void k3_attn(const unsigned short* __restrict__ WhPack,
                                               const unsigned int* __restrict__ packed,
                                               const float* __restrict__ s1,
                                               const float* __restrict__ s2,
                                               const float* __restrict__ Mv,
                                               const float* __restrict__ linv,
                                               float* __restrict__ out) {
  const int t = threadIdx.x;
  const int it = blockIdx.x;  // i-tile within batch
  const int b = blockIdx.y;
  const int i0 = it * 64;

  __shared__ float s2all[2048];       // 8 KB
  __shared__ unsigned int bits[4096]; // [64 rows][64 words], 16 KB
  __shared__ float s1v[64], Mvv[64], lvv[64];
  __shared__ unsigned short WhT[256 * 40];  // [f][j'] padded 32->40, 20 KB
  __shared__ unsigned short P[64 * 40];     // [i][j'] padded, 5 KB

  {  // stage s2 row for this batch
    const float4* src = (const float4*)(s2 + (long)b * 2048);
    ((float4*)s2all)[t] = src[t];
  }
  {  // stage packed bits for 64 rows (contiguous)
    const int4* src = (const int4*)(packed + ((long)b * 2048 + i0) * 64);
    int4* dst = (int4*)bits;
    dst[t * 2] = src[t * 2];
    dst[t * 2 + 1] = src[t * 2 + 1];
  }
  if (t < 64) {
    long r = (long)b * 2048 + i0 + t;
    s1v[t] = s1[r]; Mvv[t] = Mv[r]; lvv[t] = linv[r];
  }
  __syncthreads();

  const int wave = t >> 6, lane = t & 63;
  const int wm = wave >> 2, wn = wave & 3;  // wave tile: rows wm*32.., cols wn*64..
  const int lhi = lane >> 4, llo = lane & 15;
  const int i_p = t >> 3;            // P-compute row
  const int jl0 = (t & 7) * 4;       // P-compute j-local base

  floatx4 acc[2][4];
#pragma unroll
  for (int mt = 0; mt < 2; mt++)
#pragma unroll
    for (int nt = 0; nt < 4; nt++) acc[mt][nt] = (floatx4){0.f, 0.f, 0.f, 0.f};

  for (int jt = 0; jt < 64; jt++) {
    // stage WhT tile: 1024 x 16B chunks, perfectly coalesced loads
    const int4* wsrc = (const int4*)(WhPack + ((long)(b * 64 + jt) * 256) * 32);
#pragma unroll
    for (int rep = 0; rep < 2; rep++) {
      int cid = rep * 512 + t;
      int f = cid >> 2, c = cid & 3;
      int4 v = wsrc[cid];
      *(int4*)&WhT[f * 40 + c * 8] = v;
    }
    // compute P tile (4 probs per thread)
    {
      unsigned int w = bits[i_p * 64 + jt];
      float s1i = s1v[i_p], Mi = Mvv[i_p];
      unsigned short pb[4];
#pragma unroll
      for (int q = 0; q < 4; q++) {
        int jl = jl0 + q;
        float x = s1i + s2all[jt * 32 + jl];
        float le = x > 0.f ? x : ALPHA_LR * x;
        float pu = ((w >> jl) & 1u) ? __expf(le - Mi) : 0.f;
        pb[q] = f2bf(pu);
      }
      uint2 pk;
      pk.x = (unsigned)pb[0] | ((unsigned)pb[1] << 16);
      pk.y = (unsigned)pb[2] | ((unsigned)pb[3] << 16);
      *(uint2*)&P[i_p * 40 + jl0] = pk;
    }
    __syncthreads();

    bhalf8 af[2], bf[4];
#pragma unroll
    for (int mt = 0; mt < 2; mt++)
      af[mt] = *(const bhalf8*)&P[(wm * 32 + mt * 16 + llo) * 40 + lhi * 8];
#pragma unroll
    for (int nt = 0; nt < 4; nt++)
      bf[nt] = *(const bhalf8*)&WhT[(wn * 64 + nt * 16 + llo) * 40 + lhi * 8];
#pragma unroll
    for (int mt = 0; mt < 2; mt++)
#pragma unroll
      for (int nt = 0; nt < 4; nt++)
        acc[mt][nt] = __builtin_amdgcn_mfma_f32_16x16x32_bf16(af[mt], bf[nt], acc[mt][nt], 0, 0, 0);
    __syncthreads();
  }

  // epilogue: normalize by 1/l, ELU, store
#pragma unroll
  for (int mt = 0; mt < 2; mt++) {
#pragma unroll
    for (int nt = 0; nt < 4; nt++) {
#pragma unroll
      for (int reg = 0; reg < 4; reg++) {
        int il = wm * 32 + mt * 16 + lhi * 4 + reg;  // C/D: row=(lane>>4)*4+reg
        int f = wn * 64 + nt * 16 + llo;             // col = lane&15
        float v = acc[mt][nt][reg] * lvv[il];
        v = v > 0.f ? v : expm1f(v);
        out[((long)(b * 2048 + i0 + il)) * 256 + f] = v;
      }
    }
  }
}

// ---------------------------------------------------------------------------
extern "C" void kernel_launch(void* const* d_in, const int* in_sizes, int n_in,
                              void* d_out, int out_size, void* d_ws, size_t ws_size,
                              hipStream_t stream) {
  const float* h = (const float*)d_in[0];
  const int* adj = (const int*)d_in[1];
  const float* W = (const float*)d_in[2];
  const float* a = (const float*)d_in[3];
  float* out = (float*)d_out;

  char* ws = (char*)d_ws;
  float* Wh = (float*)ws;                                   // 16,777,216 B
  unsigned short* WhPack = (unsigned short*)(ws + 16777216); // 8,388,608 B
  float* s1 = (float*)(ws + 25165824);                      // 65,536 B
  float* s2 = (float*)(ws + 25231360);                      // 65,536 B
  float* Mv = (float*)(ws + 25296896);                      // 65,536 B
  float* linv = (float*)(ws + 25362432);                    // 65,536 B
  unsigned int* packed = (unsigned int*)(ws + 25427968);    // 4,194,304 B

  hipLaunchKernelGGL(k1_gemm, dim3(256), dim3(256), 0, stream, h, W, Wh, WhPack);
  hipLaunchKernelGGL(k1b_s, dim3(4096), dim3(256), 0, stream, Wh, a, s1, s2);
  hipLaunchKernelGGL(k2_stats, dim3(16384), dim3(256), 0, stream, adj, s1, s2, Mv, linv, packed);
  hipLaunchKernelGGL(k3_attn, dim3(32, 8), dim3(512), 0, stream, WhPack, packed, s1, s2, Mv, linv, out);
}

// Round 2
// 301.094 us; speedup vs baseline: 1.2494x; 1.2494x over previous
//
#include <hip/hip_runtime.h>

typedef __attribute__((ext_vector_type(8))) short bhalf8;
typedef __attribute__((ext_vector_type(4))) float floatx4;

#define ALPHA_LR 0.2f

__device__ __forceinline__ unsigned short f2bf(float f) {
  union { float f; unsigned int u; } v; v.f = f;
  unsigned int r = v.u + 0x7fffu + ((v.u >> 16) & 1u);
  return (unsigned short)(r >> 16);
}
__device__ __forceinline__ float bf2f(unsigned short u) {
  union { unsigned int u; float f; } v; v.u = ((unsigned int)u) << 16;
  return v.f;
}

// ---------------------------------------------------------------------------
// k0h: h fp32 -> Ahi/Alo bf16 [16384][256]  (split: x ~= hi + lo)
// ---------------------------------------------------------------------------
__global__ __launch_bounds__(256) void k0h_split(const float* __restrict__ h,
                                                 unsigned short* __restrict__ Ahi,
                                                 unsigned short* __restrict__ Alo) {
  const int idx = blockIdx.x * 256 + threadIdx.x;  // float4 index
  float4 x = ((const float4*)h)[idx];
  ushort4 hi, lo;
  float xs[4] = {x.x, x.y, x.z, x.w};
  unsigned short hs[4], ls[4];
#pragma unroll
  for (int q = 0; q < 4; q++) {
    hs[q] = f2bf(xs[q]);
    ls[q] = f2bf(xs[q] - bf2f(hs[q]));
  }
  hi = (ushort4){hs[0], hs[1], hs[2], hs[3]};
  lo = (ushort4){ls[0], ls[1], ls[2], ls[3]};
  ((ushort4*)Ahi)[idx] = hi;
  ((ushort4*)Alo)[idx] = lo;
}

// ---------------------------------------------------------------------------
// k0w: W [k][n] fp32 -> WT_hi/WT_lo bf16 [n][k] (transposed, split)
// block (16,16), grid (16,16)
// ---------------------------------------------------------------------------
__global__ void k0w_split(const float* __restrict__ W,
                          unsigned short* __restrict__ WThi,
                          unsigned short* __restrict__ WTlo) {
  __shared__ float s[16][17];
  const int tx = threadIdx.x, ty = threadIdx.y;
  const int n0 = blockIdx.x * 16, k0 = blockIdx.y * 16;
  s[ty][tx] = W[(k0 + ty) * 256 + n0 + tx];
  __syncthreads();
  float v = s[tx][ty];  // = W[k0+tx][n0+ty]
  unsigned short hi = f2bf(v);
  unsigned short lo = f2bf(v - bf2f(hi));
  WThi[(n0 + ty) * 256 + k0 + tx] = hi;
  WTlo[(n0 + ty) * 256 + k0 + tx] = lo;
}

// ---------------------------------------------------------------------------
// k1: Wh = h @ W via split-bf16 MFMA (3 passes: hi*hi + hi*lo + lo*hi).
// Writes WhPack bf16 tiled [B][jt=64][f=256][j'=32] and s1/s2 (fp32 dots with a).
// grid 256 (64-row M tiles) x 512 threads (8 waves, wave tile 32 rows x 64 f).
// LDS: A 2x33KB padded (264 shorts/row), B 2x20KB padded (40 shorts/row).
// ---------------------------------------------------------------------------
__global__ __launch_bounds__(512) void k1_mfma(const unsigned short* __restrict__ Ahi_g,
                                               const unsigned short* __restrict__ Alo_g,
                                               const unsigned short* __restrict__ Bhi_g,
                                               const unsigned short* __restrict__ Blo_g,
                                               const float* __restrict__ a_g,
                                               unsigned short* __restrict__ WhPack,
                                               float* __restrict__ s1,
                                               float* __restrict__ s2) {
  __shared__ unsigned short Ah[64 * 264], Al[64 * 264];  // 33 KB each
  __shared__ unsigned short Bh[256 * 40], Bl[256 * 40];  // 20 KB each
  __shared__ float s1red[64], s2red[64];
  const int t = threadIdx.x;
  const long r0 = (long)blockIdx.x * 64;

  if (t < 64) { s1red[t] = 0.f; s2red[t] = 0.f; }

  // stage A tiles (already bf16 in global, contiguous 32KB each)
  {
    const int4* srcH = (const int4*)(Ahi_g + r0 * 256);
    const int4* srcL = (const int4*)(Alo_g + r0 * 256);
#pragma unroll
    for (int q = 0; q < 4; q++) {
      int cid = q * 512 + t;  // 0..2047
      int row = cid >> 5, col8 = cid & 31;
      int4 vh = srcH[cid];
      int4 vl = srcL[cid];
      *(int4*)&Ah[row * 264 + col8 * 8] = vh;
      *(int4*)&Al[row * 264 + col8 * 8] = vl;
    }
  }

  const int wave = t >> 6, lane = t & 63;
  const int wm = wave >> 2, wn = wave & 3;
  const int lhi = lane >> 4, llo = lane & 15;

  floatx4 acc[2][4];
#pragma unroll
  for (int mt = 0; mt < 2; mt++)
#pragma unroll
    for (int nt = 0; nt < 4; nt++) acc[mt][nt] = (floatx4){0.f, 0.f, 0.f, 0.f};

  for (int ks = 0; ks < 8; ks++) {
    const int k0 = ks * 32;
    // prefetch B chunk (global, overlaps prev iter MFMA)
    int4 vh[2], vl[2];
#pragma unroll
    for (int q = 0; q < 2; q++) {
      int cid = q * 512 + t;  // 0..1023
      int n = cid >> 2, c = cid & 3;
      vh[q] = *(const int4*)(Bhi_g + n * 256 + k0 + c * 8);
      vl[q] = *(const int4*)(Blo_g + n * 256 + k0 + c * 8);
    }
    __syncthreads();  // prev iter frag reads done
#pragma unroll
    for (int q = 0; q < 2; q++) {
      int cid = q * 512 + t;
      int n = cid >> 2, c = cid & 3;
      *(int4*)&Bh[n * 40 + c * 8] = vh[q];
      *(int4*)&Bl[n * 40 + c * 8] = vl[q];
    }
    __syncthreads();

    bhalf8 ah[2], al[2], bh[4], bl[4];
#pragma unroll
    for (int mt = 0; mt < 2; mt++) {
      int ro = (wm * 32 + mt * 16 + llo) * 264 + k0 + lhi * 8;
      ah[mt] = *(const bhalf8*)&Ah[ro];
      al[mt] = *(const bhalf8*)&Al[ro];
    }
#pragma unroll
    for (int nt = 0; nt < 4; nt++) {
      int ro = (wn * 64 + nt * 16 + llo) * 40 + lhi * 8;
      bh[nt] = *(const bhalf8*)&Bh[ro];
      bl[nt] = *(const bhalf8*)&Bl[ro];
    }
#pragma unroll
    for (int mt = 0; mt < 2; mt++)
#pragma unroll
      for (int nt = 0; nt < 4; nt++) {
        acc[mt][nt] = __builtin_amdgcn_mfma_f32_16x16x32_bf16(ah[mt], bh[nt], acc[mt][nt], 0, 0, 0);
        acc[mt][nt] = __builtin_amdgcn_mfma_f32_16x16x32_bf16(ah[mt], bl[nt], acc[mt][nt], 0, 0, 0);
        acc[mt][nt] = __builtin_amdgcn_mfma_f32_16x16x32_bf16(al[mt], bh[nt], acc[mt][nt], 0, 0, 0);
      }
  }

  // ---- epilogue ----
  // a1/a2 for this lane's 4 f-columns
  float a1v[4], a2v[4];
#pragma unroll
  for (int nt = 0; nt < 4; nt++) {
    int f = wn * 64 + nt * 16 + llo;
    a1v[nt] = a_g[f];
    a2v[nt] = a_g[256 + f];
  }

  const int b = (int)(r0 >> 11);
  const int jt_base = (int)((r0 & 2047) >> 5);

#pragma unroll
  for (int mt = 0; mt < 2; mt++) {
    // s1/s2 partials: per (mt,reg) row, summed over this lane's 4 f's
    float p1[4], p2[4];
#pragma unroll
    for (int reg = 0; reg < 4; reg++) {
      p1[reg] = acc[mt][0][reg] * a1v[0] + acc[mt][1][reg] * a1v[1] +
                acc[mt][2][reg] * a1v[2] + acc[mt][3][reg] * a1v[3];
      p2[reg] = acc[mt][0][reg] * a2v[0] + acc[mt][1][reg] * a2v[1] +
                acc[mt][2][reg] * a2v[2] + acc[mt][3][reg] * a2v[3];
    }
#pragma unroll
    for (int off = 1; off < 16; off <<= 1) {
#pragma unroll
      for (int reg = 0; reg < 4; reg++) {
        p1[reg] += __shfl_xor(p1[reg], off);
        p2[reg] += __shfl_xor(p2[reg], off);
      }
    }
    if (llo == 0) {
#pragma unroll
      for (int reg = 0; reg < 4; reg++) {
        int il = wm * 32 + mt * 16 + lhi * 4 + reg;
        atomicAdd(&s1red[il], p1[reg]);
        atomicAdd(&s2red[il], p2[reg]);
      }
    }
    // WhPack stores: 4 consecutive j' (rows lhi*4+reg) for each (mt,nt)
#pragma unroll
    for (int nt = 0; nt < 4; nt++) {
      int f = wn * 64 + nt * 16 + llo;
      int jt = jt_base + wm;
      ushort4 pk = (ushort4){f2bf(acc[mt][nt][0]), f2bf(acc[mt][nt][1]),
                             f2bf(acc[mt][nt][2]), f2bf(acc[mt][nt][3])};
      *(ushort4*)&WhPack[((long)((b * 64 + jt) * 256 + f)) * 32 + mt * 16 + lhi * 4] = pk;
    }
  }

  __syncthreads();
  if (t < 64) {
    s1[r0 + t] = s1red[t];
    s2[r0 + t] = s2red[t];
  }
}

// ---------------------------------------------------------------------------
// K2: per row r=(b,i): M = leaky(s1 + max_{adj} s2) (leaky monotonic),
//     linv = 1/sum(exp(leaky(s1+s2_j)-M)), and pack adj row into 64 u32 words.
// ---------------------------------------------------------------------------
__global__ __launch_bounds__(256) void k2_stats(const int* __restrict__ adj,
                                                const float* __restrict__ s1,
                                                const float* __restrict__ s2,
                                                float* __restrict__ Mv,
                                                float* __restrict__ linv,
                                                unsigned int* __restrict__ packed) {
  const int t = threadIdx.x;
  const long r = blockIdx.x;
  const int b = (int)(r >> 11);
  __shared__ float red[4];
  __shared__ int redi[4];
  __shared__ unsigned char bytes[256];

  const int4* arow = (const int4*)(adj + r * 2048);
  int4 a0 = arow[t * 2], a1 = arow[t * 2 + 1];
  unsigned int m8 = (unsigned)(a0.x > 0) | ((unsigned)(a0.y > 0) << 1) |
                    ((unsigned)(a0.z > 0) << 2) | ((unsigned)(a0.w > 0) << 3) |
                    ((unsigned)(a1.x > 0) << 4) | ((unsigned)(a1.y > 0) << 5) |
                    ((unsigned)(a1.z > 0) << 6) | ((unsigned)(a1.w > 0) << 7);

  int cnt = __popc(m8);
  for (int o = 32; o; o >>= 1) cnt += __shfl_xor(cnt, o);
  if ((t & 63) == 0) redi[t >> 6] = cnt;
  __syncthreads();
  int total = redi[0] + redi[1] + redi[2] + redi[3];
  if (total == 0) m8 = 0xFFu;  // degenerate row: avoid 0/0 (prob ~0)

  const float4* s2p = (const float4*)(s2 + (long)b * 2048);
  float4 v0 = s2p[t * 2], v1 = s2p[t * 2 + 1];
  float sv[8] = {v0.x, v0.y, v0.z, v0.w, v1.x, v1.y, v1.z, v1.w};

  float mx = -INFINITY;
#pragma unroll
  for (int q = 0; q < 8; q++)
    if ((m8 >> q) & 1) mx = fmaxf(mx, sv[q]);
  for (int o = 32; o; o >>= 1) mx = fmaxf(mx, __shfl_xor(mx, o));
  if ((t & 63) == 0) red[t >> 6] = mx;
  __syncthreads();
  mx = fmaxf(fmaxf(red[0], red[1]), fmaxf(red[2], red[3]));

  const float s1i = s1[r];
  const float xm = s1i + mx;
  const float M = xm > 0.f ? xm : ALPHA_LR * xm;

  float lsum = 0.f;
#pragma unroll
  for (int q = 0; q < 8; q++) {
    if ((m8 >> q) & 1) {
      float x = s1i + sv[q];
      float le = x > 0.f ? x : ALPHA_LR * x;
      lsum += __expf(le - M);
    }
  }
  for (int o = 32; o; o >>= 1) lsum += __shfl_xor(lsum, o);
  __syncthreads();  // protect red[] reuse
  if ((t & 63) == 0) red[t >> 6] = lsum;
  __syncthreads();
  lsum = red[0] + red[1] + red[2] + red[3];

  if (t == 0) { Mv[r] = M; linv[r] = 1.f / lsum; }

  bytes[t] = (unsigned char)m8;
  __syncthreads();
  if (t < 64) {
    unsigned int w = (unsigned)bytes[t * 4] | ((unsigned)bytes[t * 4 + 1] << 8) |
                     ((unsigned)bytes[t * 4 + 2] << 16) | ((unsigned)bytes[t * 4 + 3] << 24);
    packed[r * 64 + t] = w;
  }
}

// ---------------------------------------------------------------------------
// K3: out = elu( (P @ Wh) * linv ), P on the fly from packed bits.
// grid (64, 8) x 512 threads. Block: 32 rows x 256 f. 8 waves, wave tile 16x64.
// ~40 KB LDS -> 2 blocks/CU (vs 1 before).
// ---------------------------------------------------------------------------
__global__ __launch_bounds__(512) void k3_attn(const unsigned short* __restrict__ WhPack,
                                               const unsigned int* __restrict__ packed,
                                               const float* __restrict__ s1,
                                               const float* __restrict__ s2,
                                               const float* __restrict__ Mv,
                                               const float* __restrict__ linv,
                                               float* __restrict__ out) {
  const int t = threadIdx.x;
  const int it = blockIdx.x;  // 32-row i-tile within batch
  const int b = blockIdx.y;
  const int i0 = it * 32;

  __shared__ float s2all[2048];        // 8 KB
  __shared__ unsigned int bits[2048];  // [32 rows][64 words], 8 KB
  __shared__ float s1v[32], Mvv[32], lvv[32];
  __shared__ unsigned short WhT[256 * 40];  // [f][j'] padded 32->40, 20 KB
  __shared__ unsigned short P[32 * 40];     // [i][j'] padded, 2.5 KB

  {  // stage s2 row for this batch
    const float4* src = (const float4*)(s2 + (long)b * 2048);
    ((float4*)s2all)[t] = src[t];
  }
  {  // stage packed bits for 32 rows (contiguous)
    const int4* src = (const int4*)(packed + ((long)b * 2048 + i0) * 64);
    ((int4*)bits)[t] = src[t];
  }
  if (t < 32) {
    long r = (long)b * 2048 + i0 + t;
    s1v[t] = s1[r]; Mvv[t] = Mv[r]; lvv[t] = linv[r];
  }
  __syncthreads();

  const int wave = t >> 6, lane = t & 63;
  const int wm = wave >> 2, wn = wave & 3;  // wave tile: rows wm*16.., cols wn*64..
  const int lhi = lane >> 4, llo = lane & 15;
  const int i_p = t >> 4;        // P-compute row (0..31)
  const int jl0 = (t & 15) * 2;  // P-compute j-local base

  floatx4 acc[4];
#pragma unroll
  for (int nt = 0; nt < 4; nt++) acc[nt] = (floatx4){0.f, 0.f, 0.f, 0.f};

  for (int jt = 0; jt < 64; jt++) {
    // stage WhT tile: 1024 x 16B chunks
    const int4* wsrc = (const int4*)(WhPack + ((long)(b * 64 + jt) * 256) * 32);
#pragma unroll
    for (int rep = 0; rep < 2; rep++) {
      int cid = rep * 512 + t;
      int f = cid >> 2, c = cid & 3;
      int4 v = wsrc[cid];
      *(int4*)&WhT[f * 40 + c * 8] = v;
    }
    // compute P tile (2 probs per thread)
    {
      unsigned int w = bits[i_p * 64 + jt];
      float s1i = s1v[i_p], Mi = Mvv[i_p];
      unsigned short pb[2];
#pragma unroll
      for (int q = 0; q < 2; q++) {
        int jl = jl0 + q;
        float x = s1i + s2all[jt * 32 + jl];
        float le = x > 0.f ? x : ALPHA_LR * x;
        float pu = ((w >> jl) & 1u) ? __expf(le - Mi) : 0.f;
        pb[q] = f2bf(pu);
      }
      *(unsigned int*)&P[i_p * 40 + jl0] = (unsigned)pb[0] | ((unsigned)pb[1] << 16);
    }
    __syncthreads();

    bhalf8 af = *(const bhalf8*)&P[(wm * 16 + llo) * 40 + lhi * 8];
    bhalf8 bf[4];
#pragma unroll
    for (int nt = 0; nt < 4; nt++)
      bf[nt] = *(const bhalf8*)&WhT[(wn * 64 + nt * 16 + llo) * 40 + lhi * 8];
#pragma unroll
    for (int nt = 0; nt < 4; nt++)
      acc[nt] = __builtin_amdgcn_mfma_f32_16x16x32_bf16(af, bf[nt], acc[nt], 0, 0, 0);
    __syncthreads();
  }

  // epilogue: normalize by 1/l, ELU, store
#pragma unroll
  for (int nt = 0; nt < 4; nt++) {
#pragma unroll
    for (int reg = 0; reg < 4; reg++) {
      int il = wm * 16 + lhi * 4 + reg;  // C/D: row=(lane>>4)*4+reg
      int f = wn * 64 + nt * 16 + llo;   // col = lane&15
      float v = acc[nt][reg] * lvv[il];
      v = v > 0.f ? v : expm1f(v);
      out[((long)(b * 2048 + i0 + il)) * 256 + f] = v;
    }
  }
}

// ---------------------------------------------------------------------------
extern "C" void kernel_launch(void* const* d_in, const int* in_sizes, int n_in,
                              void* d_out, int out_size, void* d_ws, size_t ws_size,
                              hipStream_t stream) {
  const float* h = (const float*)d_in[0];
  const int* adj = (const int*)d_in[1];
  const float* W = (const float*)d_in[2];
  const float* a = (const float*)d_in[3];
  float* out = (float*)d_out;

  char* ws = (char*)d_ws;
  unsigned short* WhPack = (unsigned short*)ws;              //  8,388,608 B
  unsigned short* Ahi = (unsigned short*)(ws + 8388608);     //  8,388,608 B
  unsigned short* Alo = (unsigned short*)(ws + 16777216);    //  8,388,608 B
  // packed aliases Alo's space: Alo is dead after k1, packed written in k2.
  unsigned int* packed = (unsigned int*)(ws + 16777216);     //  4,194,304 B (alias)
  unsigned short* WThi = (unsigned short*)(ws + 25165824);   //    131,072 B
  unsigned short* WTlo = (unsigned short*)(ws + 25296896);   //    131,072 B
  float* s1 = (float*)(ws + 25427968);                       //     65,536 B
  float* s2 = (float*)(ws + 25493504);                       //     65,536 B
  float* Mv = (float*)(ws + 25559040);                       //     65,536 B
  float* linv = (float*)(ws + 25624576);                     //     65,536 B

  hipLaunchKernelGGL(k0h_split, dim3(4096), dim3(256), 0, stream, h, Ahi, Alo);
  hipLaunchKernelGGL(k0w_split, dim3(16, 16), dim3(16, 16), 0, stream, W, WThi, WTlo);
  hipLaunchKernelGGL(k1_mfma, dim3(256), dim3(512), 0, stream, Ahi, Alo, WThi, WTlo, a,
                     WhPack, s1, s2);
  hipLaunchKernelGGL(k2_stats, dim3(16384), dim3(256), 0, stream, adj, s1, s2, Mv, linv, packed);
  hipLaunchKernelGGL(k3_attn, dim3(64, 8), dim3(512), 0, stream, WhPack, packed, s1, s2, Mv, linv, out);
}

// Round 3
// 265.376 us; speedup vs baseline: 1.4176x; 1.1346x over previous
//
#include <hip/hip_runtime.h>

typedef __attribute__((ext_vector_type(8))) short bhalf8;
typedef __attribute__((ext_vector_type(4))) float floatx4;

#define ALPHA_LR 0.2f

__device__ __forceinline__ unsigned short f2bf(float f) {
  union { float f; unsigned int u; } v; v.f = f;
  unsigned int r = v.u + 0x7fffu + ((v.u >> 16) & 1u);
  return (unsigned short)(r >> 16);
}
__device__ __forceinline__ float bf2f(unsigned short u) {
  union { unsigned int u; float f; } v; v.u = ((unsigned int)u) << 16;
  return v.f;
}
// async global->LDS, 16B per lane; lds ptr must be wave-uniform (HW adds lane*16)
__device__ __forceinline__ void gld16(const void* g, void* l) {
  __builtin_amdgcn_global_load_lds((const __attribute__((address_space(1))) unsigned int*)g,
                                   (__attribute__((address_space(3))) unsigned int*)l,
                                   16, 0, 0);
}

// ---------------------------------------------------------------------------
// k0w: W [k][n] fp32 -> WT_hi/WT_lo bf16, k-tiled layout [ks=8][n=256][k'=32]
// so each per-ks slice is a contiguous 16 KB blob for global_load_lds.
// ---------------------------------------------------------------------------
__global__ void k0w_split(const float* __restrict__ W,
                          unsigned short* __restrict__ WThi,
                          unsigned short* __restrict__ WTlo) {
  __shared__ float s[16][17];
  const int tx = threadIdx.x, ty = threadIdx.y;
  const int n0 = blockIdx.x * 16, k0 = blockIdx.y * 16;
  s[ty][tx] = W[(k0 + ty) * 256 + n0 + tx];
  __syncthreads();
  float v = s[tx][ty];  // = W[k0+tx][n0+ty]
  const int k = k0 + tx, n = n0 + ty;
  unsigned short hi = f2bf(v);
  unsigned short lo = f2bf(v - bf2f(hi));
  const int idx = (k >> 5) * 8192 + n * 32 + (k & 31);
  WThi[idx] = hi;
  WTlo[idx] = lo;
}

// ---------------------------------------------------------------------------
// k1: Wh = h @ W via split-bf16 MFMA (hi*hi + hi*lo + lo*hi), h split in-kernel.
// B tiles async-staged via global_load_lds, double-buffered, 1 barrier/ks.
// Writes WhPack bf16 [B][jt=64][f=256][j'=32] and s1/s2 (fp32 dots with a).
// grid 256 x 512 threads (8 waves; wave tile 32 rows x 64 f). LDS ~133 KB.
// ---------------------------------------------------------------------------
__global__ __launch_bounds__(512, 2) void k1_mfma(const float* __restrict__ h,
                                                  const unsigned short* __restrict__ Bhi_g,
                                                  const unsigned short* __restrict__ Blo_g,
                                                  const float* __restrict__ a_g,
                                                  unsigned short* __restrict__ WhPack,
                                                  float* __restrict__ s1,
                                                  float* __restrict__ s2) {
  __shared__ unsigned short Ah[64 * 264], Al[64 * 264];  // 33 KB each (pad 256->264)
  __shared__ unsigned short Bh[2][8192], Bl[2][8192];    // 16 KB per buffer
  __shared__ float s1red[64], s2red[64];
  const int t = threadIdx.x;
  const long r0 = (long)blockIdx.x * 64;
  const int wave = t >> 6, lane = t & 63;

  if (t < 64) { s1red[t] = 0.f; s2red[t] = 0.f; }

  // issue async B loads for ks=0
#pragma unroll
  for (int rep = 0; rep < 2; rep++) {
    const int off = wave * 1024 + rep * 512;  // shorts
    gld16(Bhi_g + off + lane * 8, &Bh[0][off]);
    gld16(Blo_g + off + lane * 8, &Bl[0][off]);
  }

  // stage A: read h fp32, split to hi/lo bf16 in LDS (overlaps async B loads)
#pragma unroll
  for (int q = 0; q < 8; q++) {
    int idx = q * 512 + t;  // float4 id: 64 rows x 64 cols
    int row = idx >> 6, c4 = idx & 63;
    float4 x = *(const float4*)(h + (r0 + row) * 256 + c4 * 4);
    float xs[4] = {x.x, x.y, x.z, x.w};
    unsigned short hs[4], ls[4];
#pragma unroll
    for (int qq = 0; qq < 4; qq++) {
      hs[qq] = f2bf(xs[qq]);
      ls[qq] = f2bf(xs[qq] - bf2f(hs[qq]));
    }
    *(ushort4*)&Ah[row * 264 + c4 * 4] = (ushort4){hs[0], hs[1], hs[2], hs[3]};
    *(ushort4*)&Al[row * 264 + c4 * 4] = (ushort4){ls[0], ls[1], ls[2], ls[3]};
  }
  __syncthreads();

  const int wm = wave >> 2, wn = wave & 3;
  const int lhi = lane >> 4, llo = lane & 15;

  floatx4 acc[2][4];
#pragma unroll
  for (int mt = 0; mt < 2; mt++)
#pragma unroll
    for (int nt = 0; nt < 4; nt++) acc[mt][nt] = (floatx4){0.f, 0.f, 0.f, 0.f};

  for (int ks = 0; ks < 8; ks++) {
    const int cur = ks & 1, nxt = cur ^ 1, ksn = (ks + 1) & 7;
    // issue next B tile (async, no VGPR round trip)
#pragma unroll
    for (int rep = 0; rep < 2; rep++) {
      const int off = wave * 1024 + rep * 512;
      gld16(Bhi_g + ksn * 8192 + off + lane * 8, &Bh[nxt][off]);
      gld16(Blo_g + ksn * 8192 + off + lane * 8, &Bl[nxt][off]);
    }

    const int k0 = ks * 32;
    bhalf8 ah[2], al[2], bh[4], bl[4];
#pragma unroll
    for (int mt = 0; mt < 2; mt++) {
      int ro = (wm * 32 + mt * 16 + llo) * 264 + k0 + lhi * 8;
      ah[mt] = *(const bhalf8*)&Ah[ro];
      al[mt] = *(const bhalf8*)&Al[ro];
    }
#pragma unroll
    for (int nt = 0; nt < 4; nt++) {
      int ro = (wn * 64 + nt * 16 + llo) * 32 + lhi * 8;
      bh[nt] = *(const bhalf8*)&Bh[cur][ro];
      bl[nt] = *(const bhalf8*)&Bl[cur][ro];
    }
#pragma unroll
    for (int mt = 0; mt < 2; mt++)
#pragma unroll
      for (int nt = 0; nt < 4; nt++) {
        acc[mt][nt] = __builtin_amdgcn_mfma_f32_16x16x32_bf16(ah[mt], bh[nt], acc[mt][nt], 0, 0, 0);
        acc[mt][nt] = __builtin_amdgcn_mfma_f32_16x16x32_bf16(ah[mt], bl[nt], acc[mt][nt], 0, 0, 0);
        acc[mt][nt] = __builtin_amdgcn_mfma_f32_16x16x32_bf16(al[mt], bh[nt], acc[mt][nt], 0, 0, 0);
      }
    __syncthreads();  // next buffers complete (vmcnt drained) + cur reads done
  }

  // ---- epilogue ----
  float a1v[4], a2v[4];
#pragma unroll
  for (int nt = 0; nt < 4; nt++) {
    int f = wn * 64 + nt * 16 + llo;
    a1v[nt] = a_g[f];
    a2v[nt] = a_g[256 + f];
  }

  const int b = (int)(r0 >> 11);
  const int jt_base = (int)((r0 & 2047) >> 5);

#pragma unroll
  for (int mt = 0; mt < 2; mt++) {
    float p1[4], p2[4];
#pragma unroll
    for (int reg = 0; reg < 4; reg++) {
      p1[reg] = acc[mt][0][reg] * a1v[0] + acc[mt][1][reg] * a1v[1] +
                acc[mt][2][reg] * a1v[2] + acc[mt][3][reg] * a1v[3];
      p2[reg] = acc[mt][0][reg] * a2v[0] + acc[mt][1][reg] * a2v[1] +
                acc[mt][2][reg] * a2v[2] + acc[mt][3][reg] * a2v[3];
    }
#pragma unroll
    for (int off = 1; off < 16; off <<= 1) {
#pragma unroll
      for (int reg = 0; reg < 4; reg++) {
        p1[reg] += __shfl_xor(p1[reg], off);
        p2[reg] += __shfl_xor(p2[reg], off);
      }
    }
    if (llo == 0) {
#pragma unroll
      for (int reg = 0; reg < 4; reg++) {
        int il = wm * 32 + mt * 16 + lhi * 4 + reg;
        atomicAdd(&s1red[il], p1[reg]);
        atomicAdd(&s2red[il], p2[reg]);
      }
    }
#pragma unroll
    for (int nt = 0; nt < 4; nt++) {
      int f = wn * 64 + nt * 16 + llo;
      int jt = jt_base + wm;
      ushort4 pk = (ushort4){f2bf(acc[mt][nt][0]), f2bf(acc[mt][nt][1]),
                             f2bf(acc[mt][nt][2]), f2bf(acc[mt][nt][3])};
      *(ushort4*)&WhPack[((long)((b * 64 + jt) * 256 + f)) * 32 + mt * 16 + lhi * 4] = pk;
    }
  }

  __syncthreads();
  if (t < 64) {
    s1[r0 + t] = s1red[t];
    s2[r0 + t] = s2red[t];
  }
}

// ---------------------------------------------------------------------------
// K2: per row r=(b,i): M = leaky(s1 + max_{adj} s2) (leaky monotonic),
//     linv = 1/sum(exp(leaky(s1+s2_j)-M)), and pack adj row into 64 u32 words.
// ---------------------------------------------------------------------------
__global__ __launch_bounds__(256) void k2_stats(const int* __restrict__ adj,
                                                const float* __restrict__ s1,
                                                const float* __restrict__ s2,
                                                float* __restrict__ Mv,
                                                float* __restrict__ linv,
                                                unsigned int* __restrict__ packed) {
  const int t = threadIdx.x;
  const long r = blockIdx.x;
  const int b = (int)(r >> 11);
  __shared__ float red[4];
  __shared__ int redi[4];
  __shared__ unsigned char bytes[256];

  const int4* arow = (const int4*)(adj + r * 2048);
  int4 a0 = arow[t * 2], a1 = arow[t * 2 + 1];
  unsigned int m8 = (unsigned)(a0.x > 0) | ((unsigned)(a0.y > 0) << 1) |
                    ((unsigned)(a0.z > 0) << 2) | ((unsigned)(a0.w > 0) << 3) |
                    ((unsigned)(a1.x > 0) << 4) | ((unsigned)(a1.y > 0) << 5) |
                    ((unsigned)(a1.z > 0) << 6) | ((unsigned)(a1.w > 0) << 7);

  int cnt = __popc(m8);
  for (int o = 32; o; o >>= 1) cnt += __shfl_xor(cnt, o);
  if ((t & 63) == 0) redi[t >> 6] = cnt;
  __syncthreads();
  int total = redi[0] + redi[1] + redi[2] + redi[3];
  if (total == 0) m8 = 0xFFu;  // degenerate row: avoid 0/0 (prob ~0)

  const float4* s2p = (const float4*)(s2 + (long)b * 2048);
  float4 v0 = s2p[t * 2], v1 = s2p[t * 2 + 1];
  float sv[8] = {v0.x, v0.y, v0.z, v0.w, v1.x, v1.y, v1.z, v1.w};

  float mx = -INFINITY;
#pragma unroll
  for (int q = 0; q < 8; q++)
    if ((m8 >> q) & 1) mx = fmaxf(mx, sv[q]);
  for (int o = 32; o; o >>= 1) mx = fmaxf(mx, __shfl_xor(mx, o));
  if ((t & 63) == 0) red[t >> 6] = mx;
  __syncthreads();
  mx = fmaxf(fmaxf(red[0], red[1]), fmaxf(red[2], red[3]));

  const float s1i = s1[r];
  const float xm = s1i + mx;
  const float M = fmaxf(xm, ALPHA_LR * xm);

  float lsum = 0.f;
#pragma unroll
  for (int q = 0; q < 8; q++) {
    if ((m8 >> q) & 1) {
      float x = s1i + sv[q];
      float le = fmaxf(x, ALPHA_LR * x);
      lsum += __expf(le - M);
    }
  }
  for (int o = 32; o; o >>= 1) lsum += __shfl_xor(lsum, o);
  __syncthreads();  // protect red[] reuse
  if ((t & 63) == 0) red[t >> 6] = lsum;
  __syncthreads();
  lsum = red[0] + red[1] + red[2] + red[3];

  if (t == 0) { Mv[r] = M; linv[r] = 1.f / lsum; }

  bytes[t] = (unsigned char)m8;
  __syncthreads();
  if (t < 64) {
    unsigned int w = (unsigned)bytes[t * 4] | ((unsigned)bytes[t * 4 + 1] << 8) |
                     ((unsigned)bytes[t * 4 + 2] << 16) | ((unsigned)bytes[t * 4 + 3] << 24);
    packed[r * 64 + t] = w;
  }
}

// ---------------------------------------------------------------------------
// K3: out = elu( (P @ Wh) * linv ). Single barrier per jt:
// WhT double-buffered via global_load_lds (unpadded [f][32] = dense, conflict-
// free frag reads), P double-buffered (next tile's exps computed during MFMA).
// grid (64, 8) x 512 threads; block 32 rows x 256 f; wave tile 16 x 64.
// LDS ~54 KB -> 2 blocks/CU, 4 waves/SIMD.
// ---------------------------------------------------------------------------
__global__ __launch_bounds__(512, 4) void k3_attn(const unsigned short* __restrict__ WhPack,
                                                  const unsigned int* __restrict__ packed,
                                                  const float* __restrict__ s1,
                                                  const float* __restrict__ s2,
                                                  const float* __restrict__ Mv,
                                                  const float* __restrict__ linv,
                                                  float* __restrict__ out) {
  const int t = threadIdx.x;
  const int it = blockIdx.x;
  const int b = blockIdx.y;
  const int i0 = it * 32;

  __shared__ float s2all[2048];        // 8 KB
  __shared__ unsigned int bits[2048];  // [32 rows][64 words], 8 KB
  __shared__ float s1v[32], Mvv[32], lvv[32];
  __shared__ unsigned short WhT[2][8192];  // [f=256][j'=32] unpadded, 16 KB x2
  __shared__ unsigned short P[2][1280];    // [i=32][j'=32 pad 40], 2.5 KB x2

  {
    const float4* src = (const float4*)(s2 + (long)b * 2048);
    ((float4*)s2all)[t] = src[t];
  }
  {
    const int4* src = (const int4*)(packed + ((long)b * 2048 + i0) * 64);
    ((int4*)bits)[t] = src[t];
  }
  if (t < 32) {
    long r = (long)b * 2048 + i0 + t;
    s1v[t] = s1[r]; Mvv[t] = Mv[r]; lvv[t] = linv[r];
  }
  __syncthreads();  // bits/s2all visible before P compute

  const int wave = t >> 6, lane = t & 63;
  const int wm = wave >> 2, wn = wave & 3;
  const int lhi = lane >> 4, llo = lane & 15;
  const int i_p = t >> 4;        // P-compute row (0..31)
  const int jl0 = (t & 15) * 2;  // P-compute j-local base

  const unsigned short* tbase = WhPack + ((long)b * 64) * 8192;

  // prologue: async-load tile 0, compute P tile 0
#pragma unroll
  for (int rep = 0; rep < 2; rep++) {
    const int off = wave * 1024 + rep * 512;
    gld16(tbase + off + lane * 8, &WhT[0][off]);
  }
  {
    unsigned int w = bits[i_p * 64 + 0];
    float s1i = s1v[i_p], Mi = Mvv[i_p];
    unsigned short pb[2];
#pragma unroll
    for (int q = 0; q < 2; q++) {
      int jl = jl0 + q;
      float x = s1i + s2all[jl];
      float le = fmaxf(x, ALPHA_LR * x);
      float pu = ((w >> jl) & 1u) ? __expf(le - Mi) : 0.f;
      pb[q] = f2bf(pu);
    }
    *(unsigned int*)&P[0][i_p * 40 + jl0] = (unsigned)pb[0] | ((unsigned)pb[1] << 16);
  }
  __syncthreads();

  floatx4 acc[4];
#pragma unroll
  for (int nt = 0; nt < 4; nt++) acc[nt] = (floatx4){0.f, 0.f, 0.f, 0.f};

  for (int jt = 0; jt < 64; jt++) {
    const int cur = jt & 1, nxt = cur ^ 1, jtn = (jt + 1) & 63;

    // (1) async-load next WhT tile
#pragma unroll
    for (int rep = 0; rep < 2; rep++) {
      const int off = wave * 1024 + rep * 512;
      gld16(tbase + jtn * 8192 + off + lane * 8, &WhT[nxt][off]);
    }
    // (2) compute next P tile (overlaps MFMA below via scheduler)
    {
      unsigned int w = bits[i_p * 64 + jtn];
      float s1i = s1v[i_p], Mi = Mvv[i_p];
      unsigned short pb[2];
#pragma unroll
      for (int q = 0; q < 2; q++) {
        int jl = jl0 + q;
        float x = s1i + s2all[jtn * 32 + jl];
        float le = fmaxf(x, ALPHA_LR * x);
        float pu = ((w >> jl) & 1u) ? __expf(le - Mi) : 0.f;
        pb[q] = f2bf(pu);
      }
      *(unsigned int*)&P[nxt][i_p * 40 + jl0] = (unsigned)pb[0] | ((unsigned)pb[1] << 16);
    }
    // (3) frags from current buffers, (4) MFMA
    bhalf8 af = *(const bhalf8*)&P[cur][(wm * 16 + llo) * 40 + lhi * 8];
    bhalf8 bf[4];
#pragma unroll
    for (int nt = 0; nt < 4; nt++)
      bf[nt] = *(const bhalf8*)&WhT[cur][(wn * 64 + nt * 16 + llo) * 32 + lhi * 8];
#pragma unroll
    for (int nt = 0; nt < 4; nt++)
      acc[nt] = __builtin_amdgcn_mfma_f32_16x16x32_bf16(af, bf[nt], acc[nt], 0, 0, 0);
    // (5) one barrier: drains async loads + P writes, protects cur from next overwrite
    __syncthreads();
  }

  // epilogue: normalize by 1/l, ELU, store
#pragma unroll
  for (int nt = 0; nt < 4; nt++) {
#pragma unroll
    for (int reg = 0; reg < 4; reg++) {
      int il = wm * 16 + lhi * 4 + reg;  // C/D: row=(lane>>4)*4+reg
      int f = wn * 64 + nt * 16 + llo;   // col = lane&15
      float v = acc[nt][reg] * lvv[il];
      v = v > 0.f ? v : expm1f(v);
      out[((long)(b * 2048 + i0 + il)) * 256 + f] = v;
    }
  }
}

// ---------------------------------------------------------------------------
extern "C" void kernel_launch(void* const* d_in, const int* in_sizes, int n_in,
                              void* d_out, int out_size, void* d_ws, size_t ws_size,
                              hipStream_t stream) {
  const float* h = (const float*)d_in[0];
  const int* adj = (const int*)d_in[1];
  const float* W = (const float*)d_in[2];
  const float* a = (const float*)d_in[3];
  float* out = (float*)d_out;

  char* ws = (char*)d_ws;
  unsigned short* WhPack = (unsigned short*)ws;            //  8,388,608 B
  unsigned int* packed = (unsigned int*)(ws + 8388608);    //  4,194,304 B
  unsigned short* WThi = (unsigned short*)(ws + 12582912); //    131,072 B
  unsigned short* WTlo = (unsigned short*)(ws + 12713984); //    131,072 B
  float* s1 = (float*)(ws + 12845056);                     //     65,536 B
  float* s2 = (float*)(ws + 12910592);                     //     65,536 B
  float* Mv = (float*)(ws + 12976128);                     //     65,536 B
  float* linv = (float*)(ws + 13041664);                   //     65,536 B

  hipLaunchKernelGGL(k0w_split, dim3(16, 16), dim3(16, 16), 0, stream, W, WThi, WTlo);
  hipLaunchKernelGGL(k1_mfma, dim3(256), dim3(512), 0, stream, h, WThi, WTlo, a,
                     WhPack, s1, s2);
  hipLaunchKernelGGL(k2_stats, dim3(16384), dim3(256), 0, stream, adj, s1, s2, Mv, linv, packed);
  hipLaunchKernelGGL(k3_attn, dim3(64, 8), dim3(512), 0, stream, WhPack, packed, s1, s2, Mv, linv, out);
}